// Round 10
// baseline (56.520 us; speedup 1.0000x reference)
//
#include <hip/hip_runtime.h>

typedef float f4 __attribute__((ext_vector_type(4)));
typedef float f32x4 __attribute__((ext_vector_type(4)));
typedef __bf16 bf16x8 __attribute__((ext_vector_type(8)));
typedef __bf16 bf16x4 __attribute__((ext_vector_type(4)));

#define NPSIDE 24

// Block = (b, head, 2x4 patch group), 512 threads = 8 waves.
// Wave wv -> patch (ni0 + (wv>>2), nj0 + (wv&3)).
// Shared region xs: rows 4*ni0..+11 (12), cols 4*nj0..+19 (20), 32 ch, fp32,
// clamping baked in at stage time. Plane stride 253 (=12*21+1) spreads banks.
// Q/K/V fragments are built by transform-at-read from xs (coeffs in VGPRs).
#define XS(ch_, r_, c_) xs[(ch_) * 253 + (r_) * 21 + (c_)]

__global__ __launch_bounds__(512, 2) void patch_attn(
    const float* __restrict__ x,
    const float* __restrict__ qkv_w,
    const float* __restrict__ qkv_b,
    const float* __restrict__ pos_table,
    const float* __restrict__ wmat,
    __bf16* __restrict__ mid,
    __bf16* __restrict__ wbf)
{
    __shared__ float xs[32 * 253];           // 32.4 KB
    __shared__ __bf16 Ps[8][16][72];         // 18.4 KB

    const int t = threadIdx.x;

    // side job: out_w fp32 -> bf16 fragment-linear (blocks 0..31, raw id)
    if (blockIdx.x < 32) {
        const int i = (blockIdx.x * 512 + t) * 4;   // o*256+c
        const int o = i >> 8, c = i & 255;
        const f4 v = *(const f4*)&wmat[i];
        bf16x4 ov;
        #pragma unroll
        for (int j = 0; j < 4; ++j) ov[j] = (__bf16)v[j];
        *(bf16x4*)&wbf[((o >> 4) * 8 + (c >> 5)) * 512 + (o & 15) * 32 + (c & 31)] = ov;
    }

    int raw = blockIdx.x;
    const int sw = (raw & 7) * 144 + (raw >> 3);    // XCD swizzle, 1152 = 8*144
    const int pgrp = sw % 72;
    const int bh   = sw / 72;
    const int head = bh & 7;
    const int b    = bh >> 3;
    const int ni0  = (pgrp / 6) * 2;
    const int nj0  = (pgrp % 6) * 4;
    const int c0   = head * 32;

    // ---- stage shared region (384 threads, 5 f4 each) ----
    if (t < 384) {
        const int ch  = t / 12;
        const int row = t % 12;
        const int rg  = min(4 * ni0 + row, 95);
        const float* xrow = x + (((size_t)b * 256 + c0 + ch) * 96 + rg) * 96;
        float* xdst = &XS(ch, row, 0);
        const int cb = 4 * nj0;
        #pragma unroll
        for (int cg = 0; cg < 5; ++cg) {
            const int cg4 = cb + cg * 4;
            f4 v;
            if (cg4 <= 92) {
                v = *(const f4*)&xrow[cg4];
            } else {                         // cols 96..99 -> clamp to col 95
                f4 u = *(const f4*)&xrow[92];
                v = (f4){u.w, u.w, u.w, u.w};
            }
            xdst[cg * 4 + 0] = v.x;
            xdst[cg * 4 + 1] = v.y;
            xdst[cg * 4 + 2] = v.z;
            xdst[cg * 4 + 3] = v.w;
        }
    }

    // per-lane affine coefficients (registers)
    const int wv = t >> 6, l = t & 63;
    const int l16 = l & 15, lg = l >> 4;
    const float qscale = 0.17677669529663687f;

    float kw8[8], kb8[8], qw8[8], qb8[8];
    #pragma unroll
    for (int j = 0; j < 8; ++j) {
        const int c = c0 + 8 * lg + j;
        kw8[j] = qkv_w[256 + c];
        kb8[j] = qkv_b[256 + c];
        qw8[j] = qkv_w[c] * qscale;
        qb8[j] = qkv_b[c] * qscale;
    }
    float vw2[2], vb2[2];
    #pragma unroll
    for (int nt = 0; nt < 2; ++nt) {
        const int c = c0 + nt * 16 + l16;
        vw2[nt] = qkv_w[512 + c];
        vb2[nt] = qkv_b[512 + c];
    }

    __syncthreads();

    const int wni = wv >> 2, wnj = wv & 3;
    const int ni = ni0 + wni, nj = nj0 + wnj;
    const int rb = 4 * wni, cbl = 4 * wnj;   // patch origin within region

    // ---- Q fragment (row = l16, ch = 8lg+j) ----
    bf16x8 qf;
    {
        const int qrow = rb + (l16 >> 2), qcol = cbl + (l16 & 3);
        #pragma unroll
        for (int j = 0; j < 8; ++j)
            qf[j] = (__bf16)(XS(8 * lg + j, qrow, qcol) * qw8[j] + qb8[j]);
    }

    // ---- QK^T: build K fragment per t4 and mfma ----
    const f32x4 zf = {0.f, 0.f, 0.f, 0.f};
    f32x4 sacc[4];
    #pragma unroll
    for (int t4 = 0; t4 < 4; ++t4) {
        const int px = l16 + 16 * t4;
        const int kr = rb + (px >> 3), kc = cbl + (px & 7);
        bf16x8 kf;
        #pragma unroll
        for (int j = 0; j < 8; ++j)
            kf[j] = (__bf16)(XS(8 * lg + j, kr, kc) * kw8[j] + kb8[j]);
        sacc[t4] = __builtin_amdgcn_mfma_f32_16x16x32_bf16(qf, kf, zf, 0, 0, 0);
    }

    // ---- bias + row softmax ----
    float sv[4][4], rinv[4];
    #pragma unroll
    for (int r = 0; r < 4; ++r) {
        const int qrow = lg * 4 + r;
        const int qi = qrow >> 2, qj = qrow & 3;
        float m = -1e30f;
        #pragma unroll
        for (int t4 = 0; t4 < 4; ++t4) {
            const int kcol = l16 + 16 * t4;
            const int ki = kcol >> 3, kj = kcol & 7;
            const float s = sacc[t4][r]
                + pos_table[((qi - ki + 7) * 15 + (qj - kj + 7)) * 8 + head];
            sv[t4][r] = s;
            m = fmaxf(m, s);
        }
        #pragma unroll
        for (int off = 8; off >= 1; off >>= 1)
            m = fmaxf(m, __shfl_xor(m, off, 16));
        float sum = 0.f;
        #pragma unroll
        for (int t4 = 0; t4 < 4; ++t4) {
            const float p = __expf(sv[t4][r] - m);
            sv[t4][r] = p;
            sum += p;
        }
        #pragma unroll
        for (int off = 8; off >= 1; off >>= 1)
            sum += __shfl_xor(sum, off, 16);
        rinv[r] = 1.0f / sum;
        #pragma unroll
        for (int t4 = 0; t4 < 4; ++t4)
            Ps[wv][qrow][l16 + 16 * t4] = (__bf16)sv[t4][r];
    }
    // Ps is wave-private: compiler's lgkmcnt ordering suffices, no barrier.

    // ---- PV: build V fragments from xs and mfma ----
    f32x4 oa = zf, ob = zf;
    #pragma unroll
    for (int kt = 0; kt < 2; ++kt) {
        bf16x8 pf = *(const bf16x8*)&Ps[wv][l16][lg * 8 + 32 * kt];
        bf16x8 v0, v1;
        #pragma unroll
        for (int j = 0; j < 8; ++j) {
            const int px = kt * 32 + 8 * lg + j;
            const int vr = rb + (px >> 3), vc = cbl + (px & 7);
            v0[j] = (__bf16)(XS(l16,      vr, vc) * vw2[0] + vb2[0]);
            v1[j] = (__bf16)(XS(16 + l16, vr, vc) * vw2[1] + vb2[1]);
        }
        oa = __builtin_amdgcn_mfma_f32_16x16x32_bf16(pf, v0, oa, 0, 0, 0);
        ob = __builtin_amdgcn_mfma_f32_16x16x32_bf16(pf, v1, ob, 0, 0, 0);
    }

    // ---- epilogue: store O to fragment-linear mid ----
    const int pbase = ni * 384 + lg * 96 + nj * 4;
    __bf16* mbb = mid + (size_t)b * 9216 * 256;
    #pragma unroll
    for (int r = 0; r < 4; ++r) {
        const int p = pbase + r;
        __bf16* dst = mbb + ((p >> 4) * 8 + head) * 512 + (p & 15) * 32;
        dst[l16]      = (__bf16)(oa[r] * rinv[r]);
        dst[16 + l16] = (__bf16)(ob[r] * rinv[r]);
    }
}

// y[b,o,p] = sum_c w[o,c]*mid[b,p,c]; fragment-linear operands.
// Block = 4 ptiles x 2 otiles; 16 KB w-pair staged in LDS once.
__global__ __launch_bounds__(256) void proj(
    const __bf16* __restrict__ wbf,   // fragment-linear [16][8][512]
    const __bf16* __restrict__ mid,   // fragment-linear per b [576][8][512]
    float* __restrict__ y)
{
    __shared__ __align__(16) __bf16 wlds[2][8][512];   // 16 KB

    const int t  = threadIdx.x;
    const int wv = t >> 6;
    const int l  = t & 63;
    const int l16 = l & 15, lg = l >> 4;
    const int fragoff = l16 * 32 + lg * 8;

    int raw = blockIdx.x;                     // 0..1151
    const int sw  = (raw & 7) * 144 + (raw >> 3);
    const int ptg = sw >> 3;                  // 0..143
    const int og2 = sw & 7;                   // 0..7
    const int pt  = ptg * 4 + wv;             // 0..575
    const int ot0 = og2 * 2;
    const int b   = blockIdx.z;

    // stage w pair (fully coalesced: 4 KB per instruction)
    {
        const bf16x8* wsrc = (const bf16x8*)&wbf[(size_t)ot0 * 8 * 512];
        bf16x8* wdst = (bf16x8*)&wlds[0][0][0];
        #pragma unroll
        for (int i = 0; i < 4; ++i)
            wdst[t + 256 * i] = wsrc[t + 256 * i];
    }
    __syncthreads();

    const __bf16* midb = mid + (size_t)b * 9216 * 256;

    f32x4 acc0 = {0.f, 0.f, 0.f, 0.f}, acc1 = {0.f, 0.f, 0.f, 0.f};

    #pragma unroll
    for (int kt = 0; kt < 8; ++kt) {
        const bf16x8 bfr =
            *(const bf16x8*)&midb[(size_t)(pt * 8 + kt) * 512 + fragoff];
        const bf16x8 af0 = *(const bf16x8*)&wlds[0][kt][fragoff];
        const bf16x8 af1 = *(const bf16x8*)&wlds[1][kt][fragoff];
        acc0 = __builtin_amdgcn_mfma_f32_16x16x32_bf16(af0, bfr, acc0, 0, 0, 0);
        acc1 = __builtin_amdgcn_mfma_f32_16x16x32_bf16(af1, bfr, acc1, 0, 0, 0);
    }

    const int p = pt * 16 + l16;
    #pragma unroll
    for (int ot = 0; ot < 2; ++ot) {
        const f32x4 a = ot ? acc1 : acc0;
        const int o = (ot0 + ot) * 16 + lg * 4;
        float* yb = y + ((size_t)b * 256 + o) * 9216 + p;
        #pragma unroll
        for (int r = 0; r < 4; ++r)
            yb[(size_t)r * 9216] = a[r];
    }
}

extern "C" void kernel_launch(void* const* d_in, const int* in_sizes, int n_in,
                              void* d_out, int out_size, void* d_ws, size_t ws_size,
                              hipStream_t stream) {
    const float* x         = (const float*)d_in[0];
    const float* qkv_w     = (const float*)d_in[1];
    const float* qkv_b     = (const float*)d_in[2];
    const float* out_w     = (const float*)d_in[3];
    const float* pos_table = (const float*)d_in[4];
    float* y    = (float*)d_out;
    __bf16* mid = (__bf16*)d_ws;                              // 9.4 MB
    __bf16* wbf = (__bf16*)((char*)d_ws + (12u << 20));       // 128 KB @ 12MB

    // MEASUREMENT ROUND: attn launched TWICE (idempotent: same inputs ->
    // same mid/wbf values; deterministic). attn_dur = T - 37.0; proj = 74 - T.
    patch_attn<<<dim3(1152), dim3(512), 0, stream>>>(
        x, qkv_w, qkv_b, pos_table, out_w, mid, wbf);
    patch_attn<<<dim3(1152), dim3(512), 0, stream>>>(
        x, qkv_w, qkv_b, pos_table, out_w, mid, wbf);
    proj<<<dim3(1152, 1, 2), dim3(256), 0, stream>>>(
        wbf, mid, y);
}

// Round 11
// 40.095 us; speedup vs baseline: 1.4097x; 1.4097x over previous
//
#include <hip/hip_runtime.h>

typedef float f4 __attribute__((ext_vector_type(4)));
typedef float f32x4 __attribute__((ext_vector_type(4)));
typedef __bf16 bf16x8 __attribute__((ext_vector_type(8)));
typedef __bf16 bf16x4 __attribute__((ext_vector_type(4)));

#define NPSIDE 24

// Block = (b, head, 2x4 patch group), 512 threads = 8 waves.
// Wave wv -> patch (ni0 + (wv>>2), nj0 + (wv&3)).
// Shared region xs: rows 4*ni0..+11 (12), cols 4*nj0..+19 (20), 32 ch, fp32,
// clamping baked in at stage time. Plane stride 253 (=12*21+1) spreads banks.
// Q/K/V fragments are built by transform-at-read from xs (coeffs in VGPRs).
#define XS(ch_, r_, c_) xs[(ch_) * 253 + (r_) * 21 + (c_)]

__global__ __launch_bounds__(512, 2) void patch_attn(
    const float* __restrict__ x,
    const float* __restrict__ qkv_w,
    const float* __restrict__ qkv_b,
    const float* __restrict__ pos_table,
    const float* __restrict__ wmat,
    __bf16* __restrict__ mid,
    __bf16* __restrict__ wbf)
{
    __shared__ float xs[32 * 253];           // 32.4 KB
    __shared__ __bf16 Ps[8][16][72];         // 18.4 KB

    const int t = threadIdx.x;

    // side job: out_w fp32 -> bf16 fragment-linear (blocks 0..31, raw id)
    if (blockIdx.x < 32) {
        const int i = (blockIdx.x * 512 + t) * 4;   // o*256+c
        const int o = i >> 8, c = i & 255;
        const f4 v = *(const f4*)&wmat[i];
        bf16x4 ov;
        #pragma unroll
        for (int j = 0; j < 4; ++j) ov[j] = (__bf16)v[j];
        *(bf16x4*)&wbf[((o >> 4) * 8 + (c >> 5)) * 512 + (o & 15) * 32 + (c & 31)] = ov;
    }

    int raw = blockIdx.x;
    const int sw = (raw & 7) * 144 + (raw >> 3);    // XCD swizzle, 1152 = 8*144
    const int pgrp = sw % 72;
    const int bh   = sw / 72;
    const int head = bh & 7;
    const int b    = bh >> 3;
    const int ni0  = (pgrp / 6) * 2;
    const int nj0  = (pgrp % 6) * 4;
    const int c0   = head * 32;

    // ---- stage shared region (384 threads, 5 f4 each) ----
    if (t < 384) {
        const int ch  = t / 12;
        const int row = t % 12;
        const int rg  = min(4 * ni0 + row, 95);
        const float* xrow = x + (((size_t)b * 256 + c0 + ch) * 96 + rg) * 96;
        float* xdst = &XS(ch, row, 0);
        const int cb = 4 * nj0;
        #pragma unroll
        for (int cg = 0; cg < 5; ++cg) {
            const int cg4 = cb + cg * 4;
            f4 v;
            if (cg4 <= 92) {
                v = *(const f4*)&xrow[cg4];
            } else {                         // cols 96..99 -> clamp to col 95
                f4 u = *(const f4*)&xrow[92];
                v = (f4){u.w, u.w, u.w, u.w};
            }
            xdst[cg * 4 + 0] = v.x;
            xdst[cg * 4 + 1] = v.y;
            xdst[cg * 4 + 2] = v.z;
            xdst[cg * 4 + 3] = v.w;
        }
    }

    // per-lane affine coefficients (registers)
    const int wv = t >> 6, l = t & 63;
    const int l16 = l & 15, lg = l >> 4;
    const float qscale = 0.17677669529663687f;

    float kw8[8], kb8[8], qw8[8], qb8[8];
    #pragma unroll
    for (int j = 0; j < 8; ++j) {
        const int c = c0 + 8 * lg + j;
        kw8[j] = qkv_w[256 + c];
        kb8[j] = qkv_b[256 + c];
        qw8[j] = qkv_w[c] * qscale;
        qb8[j] = qkv_b[c] * qscale;
    }
    float vw2[2], vb2[2];
    #pragma unroll
    for (int nt = 0; nt < 2; ++nt) {
        const int c = c0 + nt * 16 + l16;
        vw2[nt] = qkv_w[512 + c];
        vb2[nt] = qkv_b[512 + c];
    }

    __syncthreads();

    const int wni = wv >> 2, wnj = wv & 3;
    const int ni = ni0 + wni, nj = nj0 + wnj;
    const int rb = 4 * wni, cbl = 4 * wnj;   // patch origin within region

    // ---- Q fragment (row = l16, ch = 8lg+j) ----
    bf16x8 qf;
    {
        const int qrow = rb + (l16 >> 2), qcol = cbl + (l16 & 3);
        #pragma unroll
        for (int j = 0; j < 8; ++j)
            qf[j] = (__bf16)(XS(8 * lg + j, qrow, qcol) * qw8[j] + qb8[j]);
    }

    // ---- QK^T: build K fragment per t4 and mfma ----
    const f32x4 zf = {0.f, 0.f, 0.f, 0.f};
    f32x4 sacc[4];
    #pragma unroll
    for (int t4 = 0; t4 < 4; ++t4) {
        const int px = l16 + 16 * t4;
        const int kr = rb + (px >> 3), kc = cbl + (px & 7);
        bf16x8 kf;
        #pragma unroll
        for (int j = 0; j < 8; ++j)
            kf[j] = (__bf16)(XS(8 * lg + j, kr, kc) * kw8[j] + kb8[j]);
        sacc[t4] = __builtin_amdgcn_mfma_f32_16x16x32_bf16(qf, kf, zf, 0, 0, 0);
    }

    // ---- bias + row softmax ----
    float sv[4][4], rinv[4];
    #pragma unroll
    for (int r = 0; r < 4; ++r) {
        const int qrow = lg * 4 + r;
        const int qi = qrow >> 2, qj = qrow & 3;
        float m = -1e30f;
        #pragma unroll
        for (int t4 = 0; t4 < 4; ++t4) {
            const int kcol = l16 + 16 * t4;
            const int ki = kcol >> 3, kj = kcol & 7;
            const float s = sacc[t4][r]
                + pos_table[((qi - ki + 7) * 15 + (qj - kj + 7)) * 8 + head];
            sv[t4][r] = s;
            m = fmaxf(m, s);
        }
        #pragma unroll
        for (int off = 8; off >= 1; off >>= 1)
            m = fmaxf(m, __shfl_xor(m, off, 16));
        float sum = 0.f;
        #pragma unroll
        for (int t4 = 0; t4 < 4; ++t4) {
            const float p = __expf(sv[t4][r] - m);
            sv[t4][r] = p;
            sum += p;
        }
        #pragma unroll
        for (int off = 8; off >= 1; off >>= 1)
            sum += __shfl_xor(sum, off, 16);
        rinv[r] = 1.0f / sum;
        #pragma unroll
        for (int t4 = 0; t4 < 4; ++t4)
            Ps[wv][qrow][l16 + 16 * t4] = (__bf16)sv[t4][r];
    }
    // Ps is wave-private: compiler's lgkmcnt ordering suffices, no barrier.

    // ---- PV: build V fragments from xs and mfma ----
    f32x4 oa = zf, ob = zf;
    #pragma unroll
    for (int kt = 0; kt < 2; ++kt) {
        bf16x8 pf = *(const bf16x8*)&Ps[wv][l16][lg * 8 + 32 * kt];
        bf16x8 v0, v1;
        #pragma unroll
        for (int j = 0; j < 8; ++j) {
            const int px = kt * 32 + 8 * lg + j;
            const int vr = rb + (px >> 3), vc = cbl + (px & 7);
            v0[j] = (__bf16)(XS(l16,      vr, vc) * vw2[0] + vb2[0]);
            v1[j] = (__bf16)(XS(16 + l16, vr, vc) * vw2[1] + vb2[1]);
        }
        oa = __builtin_amdgcn_mfma_f32_16x16x32_bf16(pf, v0, oa, 0, 0, 0);
        ob = __builtin_amdgcn_mfma_f32_16x16x32_bf16(pf, v1, ob, 0, 0, 0);
    }

    // ---- epilogue: store O to fragment-linear mid ----
    const int pbase = ni * 384 + lg * 96 + nj * 4;
    __bf16* mbb = mid + (size_t)b * 9216 * 256;
    #pragma unroll
    for (int r = 0; r < 4; ++r) {
        const int p = pbase + r;
        __bf16* dst = mbb + ((p >> 4) * 8 + head) * 512 + (p & 15) * 32;
        dst[l16]      = (__bf16)(oa[r] * rinv[r]);
        dst[16 + l16] = (__bf16)(ob[r] * rinv[r]);
    }
}

// y[b,o,p] = sum_c w[o,c]*mid[b,p,c]; fragment-linear operands.
// One wave per (b, ptile, otile-half): the ptile's 8 mid fragments live in
// 32 VGPRs (loaded ONCE -> mid HBM traffic 18.8 MB, not 8x75 MB via thrashed
// L2); w (128 KB) stays L2-hot. No LDS, no barriers. 2304 blocks, 9/CU even.
__global__ __launch_bounds__(64) void proj(
    const __bf16* __restrict__ wbf,   // fragment-linear [16][8][512]
    const __bf16* __restrict__ mid,   // fragment-linear per b [576][8][512]
    float* __restrict__ y)
{
    const int l = threadIdx.x;
    const int l16 = l & 15, lg = l >> 4;
    const int fragoff = l16 * 32 + lg * 8;

    int raw = blockIdx.x;                     // 0..2303
    const int tid = (raw & 7) * 288 + (raw >> 3);   // XCD swizzle, 2304 = 8*288
    const int b   = tid / 1152;
    const int r2  = tid % 1152;
    const int pt  = r2 >> 1;                  // 0..575
    const int ot0 = (r2 & 1) * 8;             // otile half

    const __bf16* midb = mid + ((size_t)b * 9216 + (size_t)pt * 16) * 256;

    bf16x8 bfr[8];
    #pragma unroll
    for (int kt = 0; kt < 8; ++kt)
        bfr[kt] = *(const bf16x8*)&midb[kt * 512 + fragoff];

    const int p = pt * 16 + l16;
    #pragma unroll
    for (int ot = 0; ot < 8; ++ot) {
        f32x4 acc = {0.f, 0.f, 0.f, 0.f};
        #pragma unroll
        for (int kt = 0; kt < 8; ++kt) {
            const bf16x8 af =
                *(const bf16x8*)&wbf[((ot0 + ot) * 8 + kt) * 512 + fragoff];
            acc = __builtin_amdgcn_mfma_f32_16x16x32_bf16(af, bfr[kt], acc, 0, 0, 0);
        }
        const int o = (ot0 + ot) * 16 + lg * 4;
        float* yb = y + ((size_t)b * 256 + o) * 9216 + p;
        #pragma unroll
        for (int r = 0; r < 4; ++r)
            yb[(size_t)r * 9216] = acc[r];
    }
}

extern "C" void kernel_launch(void* const* d_in, const int* in_sizes, int n_in,
                              void* d_out, int out_size, void* d_ws, size_t ws_size,
                              hipStream_t stream) {
    const float* x         = (const float*)d_in[0];
    const float* qkv_w     = (const float*)d_in[1];
    const float* qkv_b     = (const float*)d_in[2];
    const float* out_w     = (const float*)d_in[3];
    const float* pos_table = (const float*)d_in[4];
    float* y    = (float*)d_out;
    __bf16* mid = (__bf16*)d_ws;                              // 9.4 MB
    __bf16* wbf = (__bf16*)((char*)d_ws + (12u << 20));       // 128 KB @ 12MB

    patch_attn<<<dim3(1152), dim3(512), 0, stream>>>(
        x, qkv_w, qkv_b, pos_table, out_w, mid, wbf);
    proj<<<dim3(2304), dim3(64), 0, stream>>>(
        wbf, mid, y);
}

// Round 12
// 35.960 us; speedup vs baseline: 1.5718x; 1.1150x over previous
//
#include <hip/hip_runtime.h>

typedef float f4 __attribute__((ext_vector_type(4)));
typedef float f32x4 __attribute__((ext_vector_type(4)));
typedef __bf16 bf16x8 __attribute__((ext_vector_type(8)));
typedef __bf16 bf16x4 __attribute__((ext_vector_type(4)));

#define NPSIDE 24

// Block = (b, head, 2x4 patch group), 512 threads = 8 waves.
// Wave wv -> patch (ni0 + (wv>>2), nj0 + (wv&3)).
// Shared region xs: rows 4*ni0..+11 (12), cols 4*nj0..+19 (20), 32 ch, fp32,
// clamping baked in at stage time. Plane stride 253 (=12*21+1) spreads banks.
// Q/K/V fragments are built by transform-at-read from xs (coeffs in VGPRs).
#define XS(ch_, r_, c_) xs[(ch_) * 253 + (r_) * 21 + (c_)]

__global__ __launch_bounds__(512, 2) void patch_attn(
    const float* __restrict__ x,
    const float* __restrict__ qkv_w,
    const float* __restrict__ qkv_b,
    const float* __restrict__ pos_table,
    const float* __restrict__ wmat,
    __bf16* __restrict__ mid,
    __bf16* __restrict__ wbf)
{
    __shared__ float xs[32 * 253];           // 32.4 KB
    __shared__ __bf16 Ps[8][16][72];         // 18.4 KB

    const int t = threadIdx.x;

    // side job: out_w fp32 -> bf16 fragment-linear (blocks 0..31, raw id)
    if (blockIdx.x < 32) {
        const int i = (blockIdx.x * 512 + t) * 4;   // o*256+c
        const int o = i >> 8, c = i & 255;
        const f4 v = *(const f4*)&wmat[i];
        bf16x4 ov;
        #pragma unroll
        for (int j = 0; j < 4; ++j) ov[j] = (__bf16)v[j];
        *(bf16x4*)&wbf[((o >> 4) * 8 + (c >> 5)) * 512 + (o & 15) * 32 + (c & 31)] = ov;
    }

    int raw = blockIdx.x;
    const int sw = (raw & 7) * 144 + (raw >> 3);    // XCD swizzle, 1152 = 8*144
    const int pgrp = sw % 72;
    const int bh   = sw / 72;
    const int head = bh & 7;
    const int b    = bh >> 3;
    const int ni0  = (pgrp / 6) * 2;
    const int nj0  = (pgrp % 6) * 4;
    const int c0   = head * 32;

    // ---- stage shared region (384 threads, 5 f4 each) ----
    if (t < 384) {
        const int ch  = t / 12;
        const int row = t % 12;
        const int rg  = min(4 * ni0 + row, 95);
        const float* xrow = x + (((size_t)b * 256 + c0 + ch) * 96 + rg) * 96;
        float* xdst = &XS(ch, row, 0);
        const int cb = 4 * nj0;
        #pragma unroll
        for (int cg = 0; cg < 5; ++cg) {
            const int cg4 = cb + cg * 4;
            f4 v;
            if (cg4 <= 92) {
                v = *(const f4*)&xrow[cg4];
            } else {                         // cols 96..99 -> clamp to col 95
                f4 u = *(const f4*)&xrow[92];
                v = (f4){u.w, u.w, u.w, u.w};
            }
            xdst[cg * 4 + 0] = v.x;
            xdst[cg * 4 + 1] = v.y;
            xdst[cg * 4 + 2] = v.z;
            xdst[cg * 4 + 3] = v.w;
        }
    }

    // per-lane affine coefficients (registers)
    const int wv = t >> 6, l = t & 63;
    const int l16 = l & 15, lg = l >> 4;
    const float qscale = 0.17677669529663687f;

    float kw8[8], kb8[8], qw8[8], qb8[8];
    #pragma unroll
    for (int j = 0; j < 8; ++j) {
        const int c = c0 + 8 * lg + j;
        kw8[j] = qkv_w[256 + c];
        kb8[j] = qkv_b[256 + c];
        qw8[j] = qkv_w[c] * qscale;
        qb8[j] = qkv_b[c] * qscale;
    }
    float vw2[2], vb2[2];
    #pragma unroll
    for (int nt = 0; nt < 2; ++nt) {
        const int c = c0 + nt * 16 + l16;
        vw2[nt] = qkv_w[512 + c];
        vb2[nt] = qkv_b[512 + c];
    }

    __syncthreads();

    const int wni = wv >> 2, wnj = wv & 3;
    const int ni = ni0 + wni, nj = nj0 + wnj;
    const int rb = 4 * wni, cbl = 4 * wnj;   // patch origin within region

    // ---- Q fragment (row = l16, ch = 8lg+j) ----
    bf16x8 qf;
    {
        const int qrow = rb + (l16 >> 2), qcol = cbl + (l16 & 3);
        #pragma unroll
        for (int j = 0; j < 8; ++j)
            qf[j] = (__bf16)(XS(8 * lg + j, qrow, qcol) * qw8[j] + qb8[j]);
    }

    // ---- QK^T: build K fragment per t4 and mfma ----
    const f32x4 zf = {0.f, 0.f, 0.f, 0.f};
    f32x4 sacc[4];
    #pragma unroll
    for (int t4 = 0; t4 < 4; ++t4) {
        const int px = l16 + 16 * t4;
        const int kr = rb + (px >> 3), kc = cbl + (px & 7);
        bf16x8 kf;
        #pragma unroll
        for (int j = 0; j < 8; ++j)
            kf[j] = (__bf16)(XS(8 * lg + j, kr, kc) * kw8[j] + kb8[j]);
        sacc[t4] = __builtin_amdgcn_mfma_f32_16x16x32_bf16(qf, kf, zf, 0, 0, 0);
    }

    // ---- bias + row softmax ----
    float sv[4][4], rinv[4];
    #pragma unroll
    for (int r = 0; r < 4; ++r) {
        const int qrow = lg * 4 + r;
        const int qi = qrow >> 2, qj = qrow & 3;
        float m = -1e30f;
        #pragma unroll
        for (int t4 = 0; t4 < 4; ++t4) {
            const int kcol = l16 + 16 * t4;
            const int ki = kcol >> 3, kj = kcol & 7;
            const float s = sacc[t4][r]
                + pos_table[((qi - ki + 7) * 15 + (qj - kj + 7)) * 8 + head];
            sv[t4][r] = s;
            m = fmaxf(m, s);
        }
        #pragma unroll
        for (int off = 8; off >= 1; off >>= 1)
            m = fmaxf(m, __shfl_xor(m, off, 16));
        float sum = 0.f;
        #pragma unroll
        for (int t4 = 0; t4 < 4; ++t4) {
            const float p = __expf(sv[t4][r] - m);
            sv[t4][r] = p;
            sum += p;
        }
        #pragma unroll
        for (int off = 8; off >= 1; off >>= 1)
            sum += __shfl_xor(sum, off, 16);
        rinv[r] = 1.0f / sum;
        #pragma unroll
        for (int t4 = 0; t4 < 4; ++t4)
            Ps[wv][qrow][l16 + 16 * t4] = (__bf16)sv[t4][r];
    }
    // Ps is wave-private: compiler's lgkmcnt ordering suffices, no barrier.

    // ---- PV: build V fragments from xs and mfma ----
    f32x4 oa = zf, ob = zf;
    #pragma unroll
    for (int kt = 0; kt < 2; ++kt) {
        bf16x8 pf = *(const bf16x8*)&Ps[wv][l16][lg * 8 + 32 * kt];
        bf16x8 v0, v1;
        #pragma unroll
        for (int j = 0; j < 8; ++j) {
            const int px = kt * 32 + 8 * lg + j;
            const int vr = rb + (px >> 3), vc = cbl + (px & 7);
            v0[j] = (__bf16)(XS(l16,      vr, vc) * vw2[0] + vb2[0]);
            v1[j] = (__bf16)(XS(16 + l16, vr, vc) * vw2[1] + vb2[1]);
        }
        oa = __builtin_amdgcn_mfma_f32_16x16x32_bf16(pf, v0, oa, 0, 0, 0);
        ob = __builtin_amdgcn_mfma_f32_16x16x32_bf16(pf, v1, ob, 0, 0, 0);
    }

    // ---- epilogue: store O to fragment-linear mid ----
    const int pbase = ni * 384 + lg * 96 + nj * 4;
    __bf16* mbb = mid + (size_t)b * 9216 * 256;
    #pragma unroll
    for (int r = 0; r < 4; ++r) {
        const int p = pbase + r;
        __bf16* dst = mbb + ((p >> 4) * 8 + head) * 512 + (p & 15) * 32;
        dst[l16]      = (__bf16)(oa[r] * rinv[r]);
        dst[16 + l16] = (__bf16)(ob[r] * rinv[r]);
    }
}

// y[b,o,p] = sum_c w[o,c]*mid[b,p,c]; fragment-linear operands.
// Block = 4 waves; stages a 4-otile w slab (32 KB) once; wave wv owns ptile
// pt = chunk*4+wv across ALL 4 staged otiles: 32 MFMA : 8 global loads.
// Job map (1152 blocks): XCD k gets exclusive chunks [18k,18k+18) with
// (b, og4) INNERMOST -> 8 consecutive same-XCD blocks reuse one 64 KB mid
// chunk from L2; mid HBM fetch stays ~9.4 MB. 4.5 blocks/CU, LDS 32 KB.
__global__ __launch_bounds__(256) void proj(
    const __bf16* __restrict__ wbf,   // fragment-linear [16][8][512]
    const __bf16* __restrict__ mid,   // fragment-linear per b [576][8][512]
    float* __restrict__ y)
{
    __shared__ __align__(16) __bf16 wlds[4][8][512];   // 32 KB

    const int t  = threadIdx.x;
    const int wv = t >> 6;
    const int l  = t & 63;
    const int l16 = l & 15, lg = l >> 4;
    const int fragoff = l16 * 32 + lg * 8;

    const int raw = blockIdx.x;               // 0..1151
    const int xcd = raw & 7;
    const int seq = raw >> 3;                 // 0..143 within XCD
    const int chunk = xcd * 18 + (seq >> 3);  // exclusive 18-chunk slice
    const int rem   = seq & 7;
    const int b     = rem >> 2;
    const int og4   = rem & 3;
    const int ot0   = og4 * 4;
    const int pt    = chunk * 4 + wv;         // 0..575

    // stage 32 KB w slab (4 KB per instruction, fully coalesced)
    {
        const bf16x8* wsrc = (const bf16x8*)&wbf[(size_t)ot0 * 8 * 512];
        bf16x8* wdst = (bf16x8*)&wlds[0][0][0];
        #pragma unroll
        for (int i = 0; i < 8; ++i)
            wdst[t + 256 * i] = wsrc[t + 256 * i];
    }
    __syncthreads();

    // ptile's 8 mid fragments -> registers (read once)
    const __bf16* midb = mid + ((size_t)b * 9216 + (size_t)pt * 16) * 256;
    bf16x8 bfr[8];
    #pragma unroll
    for (int kt = 0; kt < 8; ++kt)
        bfr[kt] = *(const bf16x8*)&midb[kt * 512 + fragoff];

    f32x4 acc[4];
    #pragma unroll
    for (int ot = 0; ot < 4; ++ot) acc[ot] = (f32x4){0.f, 0.f, 0.f, 0.f};

    #pragma unroll
    for (int ot = 0; ot < 4; ++ot)
        #pragma unroll
        for (int kt = 0; kt < 8; ++kt) {
            const bf16x8 af = *(const bf16x8*)&wlds[ot][kt][fragoff];
            acc[ot] = __builtin_amdgcn_mfma_f32_16x16x32_bf16(af, bfr[kt], acc[ot], 0, 0, 0);
        }

    const int p = pt * 16 + l16;
    #pragma unroll
    for (int ot = 0; ot < 4; ++ot) {
        const int o = (ot0 + ot) * 16 + lg * 4;
        float* yb = y + ((size_t)b * 256 + o) * 9216 + p;
        #pragma unroll
        for (int r = 0; r < 4; ++r)
            yb[(size_t)r * 9216] = acc[ot][r];
    }
}

extern "C" void kernel_launch(void* const* d_in, const int* in_sizes, int n_in,
                              void* d_out, int out_size, void* d_ws, size_t ws_size,
                              hipStream_t stream) {
    const float* x         = (const float*)d_in[0];
    const float* qkv_w     = (const float*)d_in[1];
    const float* qkv_b     = (const float*)d_in[2];
    const float* out_w     = (const float*)d_in[3];
    const float* pos_table = (const float*)d_in[4];
    float* y    = (float*)d_out;
    __bf16* mid = (__bf16*)d_ws;                              // 9.4 MB
    __bf16* wbf = (__bf16*)((char*)d_ws + (12u << 20));       // 128 KB @ 12MB

    patch_attn<<<dim3(1152), dim3(512), 0, stream>>>(
        x, qkv_w, qkv_b, pos_table, out_w, mid, wbf);
    proj<<<dim3(1152), dim3(256), 0, stream>>>(
        wbf, mid, y);
}

// Round 13
// 34.785 us; speedup vs baseline: 1.6248x; 1.0338x over previous
//
#include <hip/hip_runtime.h>

typedef float f4 __attribute__((ext_vector_type(4)));
typedef float f32x4 __attribute__((ext_vector_type(4)));
typedef __bf16 bf16x8 __attribute__((ext_vector_type(8)));
typedef __bf16 bf16x4 __attribute__((ext_vector_type(4)));

#define NPSIDE 24

// Block = (b, head, 1x4 patch strip), 256 threads = 4 waves, wave = 1 patch.
// Region: pixel rows 4ni..4ni+7 (exactly the strip's k-windows -> NO vertical
// halo), cols 4*nj0..+19, 32 ch fp32, clamping baked in. 30.8 KB LDS ->
// 5 blocks/CU (phase overlap across blocks). Fragments built transform-at-read.
#define XS(ch_, r_, c_) xs[(ch_) * 169 + (r_) * 21 + (c_)]

__global__ __launch_bounds__(256, 4) void patch_attn(
    const float* __restrict__ x,
    const float* __restrict__ qkv_w,
    const float* __restrict__ qkv_b,
    const float* __restrict__ pos_table,
    const float* __restrict__ wmat,
    __bf16* __restrict__ mid,
    __bf16* __restrict__ wbf)
{
    __shared__ float xs[32 * 169];           // 21.6 KB
    __shared__ __bf16 Ps[4][16][72];         // 9.2 KB   total 30.8 KB

    const int t = threadIdx.x;

    // side job: out_w fp32 -> bf16 fragment-linear (blocks 0..63, raw id)
    if (blockIdx.x < 64) {
        const int i = (blockIdx.x * 256 + t) * 4;   // o*256+c
        const int o = i >> 8, c = i & 255;
        const f4 v = *(const f4*)&wmat[i];
        bf16x4 ov;
        #pragma unroll
        for (int j = 0; j < 4; ++j) ov[j] = (__bf16)v[j];
        *(bf16x4*)&wbf[((o >> 4) * 8 + (c >> 5)) * 512 + (o & 15) * 32 + (c & 31)] = ov;
    }

    const int raw = blockIdx.x;
    const int sw  = (raw & 7) * 288 + (raw >> 3);   // XCD swizzle, 2304 = 8*288
    const int bh  = sw / 144;                 // (b, head)
    const int r   = sw % 144;
    const int head = bh & 7;
    const int b    = bh >> 3;
    const int ni   = r / 6;                   // patch row 0..23
    const int nj0p = (r % 6) * 4;             // first patch col of strip
    const int c0   = head * 32;

    // ---- stage region: 1280 f4 = 5 per thread, none idle ----
    #pragma unroll
    for (int i = 0; i < 5; ++i) {
        const int idx = i * 256 + t;          // (ch, row, cg)
        const int ch  = idx / 40;
        const int rem = idx % 40;
        const int row = rem / 5, cg = rem % 5;
        const int rg  = min(4 * ni + row, 95);
        const int cg4 = 16 * (r % 6) + 4 * cg;
        const float* xrow = x + (((size_t)b * 256 + c0 + ch) * 96 + rg) * 96;
        f4 v;
        if (cg4 <= 92) {
            v = *(const f4*)&xrow[cg4];
        } else {                              // cols 96..99 clamp to col 95
            const float s = xrow[95];
            v = (f4){s, s, s, s};
        }
        float* xdst = &XS(ch, row, 4 * cg);
        xdst[0] = v.x; xdst[1] = v.y; xdst[2] = v.z; xdst[3] = v.w;
    }

    // per-lane affine coefficients (registers)
    const int wv = t >> 6, l = t & 63;
    const int l16 = l & 15, lg = l >> 4;
    const float qscale = 0.17677669529663687f;

    float kw8[8], kb8[8], qw8[8], qb8[8];
    #pragma unroll
    for (int j = 0; j < 8; ++j) {
        const int c = c0 + 8 * lg + j;
        kw8[j] = qkv_w[256 + c];
        kb8[j] = qkv_b[256 + c];
        qw8[j] = qkv_w[c] * qscale;
        qb8[j] = qkv_b[c] * qscale;
    }
    float vw2[2], vb2[2];
    #pragma unroll
    for (int nt = 0; nt < 2; ++nt) {
        const int c = c0 + nt * 16 + l16;
        vw2[nt] = qkv_w[512 + c];
        vb2[nt] = qkv_b[512 + c];
    }

    __syncthreads();

    const int nj  = nj0p + wv;
    const int cbl = 4 * wv;                  // patch origin col within region

    // ---- Q fragment (row = l16, ch = 8lg+j) ----
    bf16x8 qf;
    {
        const int qrow = l16 >> 2, qcol = cbl + (l16 & 3);
        #pragma unroll
        for (int j = 0; j < 8; ++j)
            qf[j] = (__bf16)(XS(8 * lg + j, qrow, qcol) * qw8[j] + qb8[j]);
    }

    // ---- QK^T: build K fragment per t4 and mfma ----
    const f32x4 zf = {0.f, 0.f, 0.f, 0.f};
    f32x4 sacc[4];
    #pragma unroll
    for (int t4 = 0; t4 < 4; ++t4) {
        const int px = l16 + 16 * t4;
        const int kr = px >> 3, kc = cbl + (px & 7);
        bf16x8 kf;
        #pragma unroll
        for (int j = 0; j < 8; ++j)
            kf[j] = (__bf16)(XS(8 * lg + j, kr, kc) * kw8[j] + kb8[j]);
        sacc[t4] = __builtin_amdgcn_mfma_f32_16x16x32_bf16(qf, kf, zf, 0, 0, 0);
    }

    // ---- bias + row softmax ----
    float sv[4][4], rinv[4];
    #pragma unroll
    for (int rr = 0; rr < 4; ++rr) {
        const int qrow = lg * 4 + rr;
        const int qi = qrow >> 2, qj = qrow & 3;
        float m = -1e30f;
        #pragma unroll
        for (int t4 = 0; t4 < 4; ++t4) {
            const int kcol = l16 + 16 * t4;
            const int ki = kcol >> 3, kj = kcol & 7;
            const float s = sacc[t4][rr]
                + pos_table[((qi - ki + 7) * 15 + (qj - kj + 7)) * 8 + head];
            sv[t4][rr] = s;
            m = fmaxf(m, s);
        }
        #pragma unroll
        for (int off = 8; off >= 1; off >>= 1)
            m = fmaxf(m, __shfl_xor(m, off, 16));
        float sum = 0.f;
        #pragma unroll
        for (int t4 = 0; t4 < 4; ++t4) {
            const float p = __expf(sv[t4][rr] - m);
            sv[t4][rr] = p;
            sum += p;
        }
        #pragma unroll
        for (int off = 8; off >= 1; off >>= 1)
            sum += __shfl_xor(sum, off, 16);
        rinv[rr] = 1.0f / sum;
        #pragma unroll
        for (int t4 = 0; t4 < 4; ++t4)
            Ps[wv][qrow][l16 + 16 * t4] = (__bf16)sv[t4][rr];
    }
    // Ps is wave-private: compiler's lgkmcnt ordering suffices, no barrier.

    // ---- PV: build V fragments from xs and mfma ----
    f32x4 oa = zf, ob = zf;
    #pragma unroll
    for (int kt = 0; kt < 2; ++kt) {
        bf16x8 pf = *(const bf16x8*)&Ps[wv][l16][lg * 8 + 32 * kt];
        bf16x8 v0, v1;
        #pragma unroll
        for (int j = 0; j < 8; ++j) {
            const int px = kt * 32 + 8 * lg + j;
            const int vr = px >> 3, vc = cbl + (px & 7);
            v0[j] = (__bf16)(XS(l16,      vr, vc) * vw2[0] + vb2[0]);
            v1[j] = (__bf16)(XS(16 + l16, vr, vc) * vw2[1] + vb2[1]);
        }
        oa = __builtin_amdgcn_mfma_f32_16x16x32_bf16(pf, v0, oa, 0, 0, 0);
        ob = __builtin_amdgcn_mfma_f32_16x16x32_bf16(pf, v1, ob, 0, 0, 0);
    }

    // ---- epilogue: store O to fragment-linear mid ----
    const int pbase = ni * 384 + lg * 96 + nj * 4;
    __bf16* mbb = mid + (size_t)b * 9216 * 256;
    #pragma unroll
    for (int rr = 0; rr < 4; ++rr) {
        const int p = pbase + rr;
        __bf16* dst = mbb + ((p >> 4) * 8 + head) * 512 + (p & 15) * 32;
        dst[l16]      = (__bf16)(oa[rr] * rinv[rr]);
        dst[16 + l16] = (__bf16)(ob[rr] * rinv[rr]);
    }
}

// y[b,o,p] = sum_c w[o,c]*mid[b,p,c]; fragment-linear operands. (R12, frozen)
__global__ __launch_bounds__(256) void proj(
    const __bf16* __restrict__ wbf,   // fragment-linear [16][8][512]
    const __bf16* __restrict__ mid,   // fragment-linear per b [576][8][512]
    float* __restrict__ y)
{
    __shared__ __align__(16) __bf16 wlds[4][8][512];   // 32 KB

    const int t  = threadIdx.x;
    const int wv = t >> 6;
    const int l  = t & 63;
    const int l16 = l & 15, lg = l >> 4;
    const int fragoff = l16 * 32 + lg * 8;

    const int raw = blockIdx.x;               // 0..1151
    const int xcd = raw & 7;
    const int seq = raw >> 3;                 // 0..143 within XCD
    const int chunk = xcd * 18 + (seq >> 3);  // exclusive 18-chunk slice
    const int rem   = seq & 7;
    const int b     = rem >> 2;
    const int og4   = rem & 3;
    const int ot0   = og4 * 4;
    const int pt    = chunk * 4 + wv;         // 0..575

    // stage 32 KB w slab (4 KB per instruction, fully coalesced)
    {
        const bf16x8* wsrc = (const bf16x8*)&wbf[(size_t)ot0 * 8 * 512];
        bf16x8* wdst = (bf16x8*)&wlds[0][0][0];
        #pragma unroll
        for (int i = 0; i < 8; ++i)
            wdst[t + 256 * i] = wsrc[t + 256 * i];
    }
    __syncthreads();

    // ptile's 8 mid fragments -> registers (read once)
    const __bf16* midb = mid + ((size_t)b * 9216 + (size_t)pt * 16) * 256;
    bf16x8 bfr[8];
    #pragma unroll
    for (int kt = 0; kt < 8; ++kt)
        bfr[kt] = *(const bf16x8*)&midb[kt * 512 + fragoff];

    f32x4 acc[4];
    #pragma unroll
    for (int ot = 0; ot < 4; ++ot) acc[ot] = (f32x4){0.f, 0.f, 0.f, 0.f};

    #pragma unroll
    for (int ot = 0; ot < 4; ++ot)
        #pragma unroll
        for (int kt = 0; kt < 8; ++kt) {
            const bf16x8 af = *(const bf16x8*)&wlds[ot][kt][fragoff];
            acc[ot] = __builtin_amdgcn_mfma_f32_16x16x32_bf16(af, bfr[kt], acc[ot], 0, 0, 0);
        }

    const int p = pt * 16 + l16;
    #pragma unroll
    for (int ot = 0; ot < 4; ++ot) {
        const int o = (ot0 + ot) * 16 + lg * 4;
        float* yb = y + ((size_t)b * 256 + o) * 9216 + p;
        #pragma unroll
        for (int r = 0; r < 4; ++r)
            yb[(size_t)r * 9216] = acc[ot][r];
    }
}

extern "C" void kernel_launch(void* const* d_in, const int* in_sizes, int n_in,
                              void* d_out, int out_size, void* d_ws, size_t ws_size,
                              hipStream_t stream) {
    const float* x         = (const float*)d_in[0];
    const float* qkv_w     = (const float*)d_in[1];
    const float* qkv_b     = (const float*)d_in[2];
    const float* out_w     = (const float*)d_in[3];
    const float* pos_table = (const float*)d_in[4];
    float* y    = (float*)d_out;
    __bf16* mid = (__bf16*)d_ws;                              // 9.4 MB
    __bf16* wbf = (__bf16*)((char*)d_ws + (12u << 20));       // 128 KB @ 12MB

    patch_attn<<<dim3(2304), dim3(256), 0, stream>>>(
        x, qkv_w, qkv_b, pos_table, out_w, mid, wbf);
    proj<<<dim3(1152), dim3(256), 0, stream>>>(
        wbf, mid, y);
}